// Round 3
// baseline (121.551 us; speedup 1.0000x reference)
//
#include <hip/hip_runtime.h>

// Deformable conv (K=3, stride=1, pad=1, dil=1), N=8, Cin=Cout=128, H=W=64.
// R3: LDS-staged weights via async global_load_lds (width=16) hidden under the
//     sampling VALU; block = 64 wo x 128 cout (M=64), 3 blocks/CU; LDS-transposed
//     coalesced epilogue; prep fused into one kernel. 2 launches total.
// ws: xt (NHWC bf16) 8 MB at +0 ; wtf (frag-major bf16) 288 KB at +8388608.

#define H  64
#define W  64
#define CIN 128
#define COUT 128
#define NB 8
#define KK 9

typedef short bf16x8 __attribute__((ext_vector_type(8)));
typedef float f32x4  __attribute__((ext_vector_type(4)));
typedef __attribute__((address_space(3))) unsigned int lds_u32;
typedef __attribute__((address_space(1))) const unsigned int gbl_u32;

__device__ __forceinline__ unsigned short f2bf(float f) {
    unsigned u = __builtin_bit_cast(unsigned, f);
    u += 0x7FFFu + ((u >> 16) & 1u);          // round-nearest-even
    return (unsigned short)(u >> 16);
}
__device__ __forceinline__ float lo_f(unsigned u) { return __builtin_bit_cast(float, u << 16); }
__device__ __forceinline__ float hi_f(unsigned u) { return __builtin_bit_cast(float, u & 0xFFFF0000u); }

// Fused prep: all 512 blocks transpose x NCHW fp32 -> NHWC bf16 (one (n,y) row each);
// blocks 0..71 additionally build wtf frag-major: [kk][nt:8][ct:4][lane:64][j:8].
// B-frag mapping (verified R1/R2): co = 16*nt + (lane&15), c = 32*ct + 8*(lane>>4) + j.
__global__ void prep_all(const float* __restrict__ x, const float* __restrict__ w,
                         unsigned short* __restrict__ xt, unsigned short* __restrict__ wtf) {
    if (blockIdx.x < 72) {
        int id = blockIdx.x * 256 + threadIdx.x;   // 18432 ids
        int lane = id & 63;
        int ct = (id >> 6) & 3;
        int nt = (id >> 8) & 7;
        int kk = id >> 11;
        int co = nt * 16 + (lane & 15);
        int c0 = ct * 32 + (lane >> 4) * 8;
        unsigned short v[8];
        #pragma unroll
        for (int j = 0; j < 8; ++j)
            v[j] = f2bf(w[((size_t)co * CIN + c0 + j) * KK + kk]);
        *(uint4*)(wtf + (size_t)id * 8) = *(const uint4*)v;
    }
    __shared__ float tile[CIN][W + 1];
    int b = blockIdx.x;                 // n*64 + y
    int n = b >> 6, y = b & 63;
    int t = threadIdx.x;
    int l = t & 63, g = t >> 6;
    const float* src = x + ((size_t)n * CIN * H + y) * W;
    #pragma unroll
    for (int i = 0; i < 32; ++i) {
        int c = g * 32 + i;
        tile[c][l] = src[(size_t)c * H * W + l];   // coalesced 256B row per wave
    }
    __syncthreads();
    int xp = t & 63;                    // lane-major x => conflict-free LDS reads
    int cb = (t >> 6) * 32;
    unsigned short* dst = xt + (((size_t)(n * H + y) * W + xp) * CIN + cb);
    unsigned rr[16];
    #pragma unroll
    for (int i = 0; i < 16; ++i) {
        rr[i] = (unsigned)f2bf(tile[cb + 2 * i][xp])
              | ((unsigned)f2bf(tile[cb + 2 * i + 1][xp]) << 16);
    }
    #pragma unroll
    for (int i = 0; i < 4; ++i)
        ((uint4*)dst)[i] = make_uint4(rr[4*i], rr[4*i+1], rr[4*i+2], rr[4*i+3]);
}

// Block = (n, ho): 64 wo x 128 cout. 256 threads = 4 waves.
// Wave wv = m-tile wv (16 wo) x all 128 co (8 n-tiles); acc = 8 x f32x4.
// Per kk: async-DMA wts[kk] (32KB) global->LDS, sample 64 pos x 128 ch -> LDS,
// barrier, 32 MFMA from LDS, barrier.
__global__ __launch_bounds__(256, 3) void deform_main(
        const float* __restrict__ offs, const unsigned short* __restrict__ xt,
        const unsigned short* __restrict__ wtf, float* __restrict__ out) {
    __shared__ __attribute__((aligned(16))) char lds_raw[50176];
    unsigned short* samp = (unsigned short*)lds_raw;            // [64][136] bf16
    unsigned short* wts  = (unsigned short*)(lds_raw + 17408);  // [16384] bf16 (32KB)
    float* ot            = (float*)lds_raw;                     // [128][65] f32 epilogue

    int b = blockIdx.x;
    int n = b >> 6, ho = b & 63;
    int t = threadIdx.x;
    int lane = t & 63, wv = t >> 6;
    int lm = lane & 15, lq = lane >> 4;

    // sampling role: position p (0..63), 32-channel chunk cb
    int p  = t >> 2;
    int cb = (t & 3) << 5;
    const float* offp = offs + (((size_t)n * 2 * KK) * H + ho) * W + p;
    const unsigned short* xbase = xt + (size_t)n * H * W * CIN + cb;

    f32x4 acc[8] = {};

    float dy = offp[0];
    float dx = offp[(size_t)H * W];
    int kh = 0, kw = 0;
    for (int kk = 0; kk < KK; ++kk) {
        // ---- async stage wts[kk]: wave wv copies its 8KB quarter (DMA, no VGPR) ----
        {
            const unsigned short* gb = wtf + (size_t)kk * 16384 + wv * 4096;
            unsigned short* lb = wts + wv * 4096;
            #pragma unroll
            for (int i = 0; i < 8; ++i)
                __builtin_amdgcn_global_load_lds((gbl_u32*)(gb + i * 512 + lane * 8),
                                                 (lds_u32*)(lb + i * 512), 16, 0, 0);
        }
        // ---- bilinear-sample 32 channels at (ho, p, kk) ----
        float py = (float)(ho - 1 + kh) + dy;
        float px = (float)(p  - 1 + kw) + dx;
        float y0f = floorf(py), x0f = floorf(px);
        float wy1 = py - y0f, wx1 = px - x0f;
        float wy0 = 1.f - wy1, wx0 = 1.f - wx1;
        int y0 = (int)y0f, x0 = (int)x0f;
        int y1 = y0 + 1, x1 = x0 + 1;
        bool vy0 = (unsigned)y0 < (unsigned)H, vy1 = (unsigned)y1 < (unsigned)H;
        bool vx0 = (unsigned)x0 < (unsigned)W, vx1 = (unsigned)x1 < (unsigned)W;
        float w00 = (vy0 && vx0) ? wy0 * wx0 : 0.f;
        float w01 = (vy0 && vx1) ? wy0 * wx1 : 0.f;
        float w10 = (vy1 && vx0) ? wy1 * wx0 : 0.f;
        float w11 = (vy1 && vx1) ? wy1 * wx1 : 0.f;
        int yc0 = min(max(y0, 0), H - 1), yc1 = min(max(y1, 0), H - 1);
        int xc0 = min(max(x0, 0), W - 1), xc1 = min(max(x1, 0), W - 1);
        const unsigned short* r0 = xbase + (size_t)yc0 * (W * CIN);
        const unsigned short* r1 = xbase + (size_t)yc1 * (W * CIN);
        const unsigned short* b00 = r0 + (xc0 << 7);
        const unsigned short* b01 = r0 + (xc1 << 7);
        const unsigned short* b10 = r1 + (xc0 << 7);
        const unsigned short* b11 = r1 + (xc1 << 7);
        unsigned short* sdst = samp + p * 136 + cb;
        #pragma unroll
        for (int j = 0; j < 4; ++j) {
            uint4 q00 = *(const uint4*)(b00 + 8 * j);
            uint4 q01 = *(const uint4*)(b01 + 8 * j);
            uint4 q10 = *(const uint4*)(b10 + 8 * j);
            uint4 q11 = *(const uint4*)(b11 + 8 * j);
            const unsigned* a0 = (const unsigned*)&q00;
            const unsigned* a1 = (const unsigned*)&q01;
            const unsigned* a2 = (const unsigned*)&q10;
            const unsigned* a3 = (const unsigned*)&q11;
            unsigned rr[4];
            #pragma unroll
            for (int i = 0; i < 4; ++i) {
                float v0 = w00*lo_f(a0[i]) + w01*lo_f(a1[i]) + w10*lo_f(a2[i]) + w11*lo_f(a3[i]);
                float v1 = w00*hi_f(a0[i]) + w01*hi_f(a1[i]) + w10*hi_f(a2[i]) + w11*hi_f(a3[i]);
                rr[i] = (unsigned)f2bf(v0) | ((unsigned)f2bf(v1) << 16);
            }
            *(uint4*)(sdst + 8 * j) = make_uint4(rr[0], rr[1], rr[2], rr[3]);
        }
        // prefetch next kk's offsets before the barrier
        if (kk < KK - 1) {
            dy = offp[(size_t)(2 * kk + 2) * H * W];
            dx = offp[(size_t)(2 * kk + 3) * H * W];
        }
        ++kw; if (kw == 3) { kw = 0; ++kh; }
        __syncthreads();     // samp written + wts DMA drained + prev MFMA reads done
        // ---- 32 MFMA: A = samp rows (m=wo), B^T = wts frags (n=co) ----
        const unsigned short* arow = samp + (wv * 16 + lm) * 136 + (lq << 3);
        const unsigned short* bbase = wts + (lane << 3);
        #pragma unroll
        for (int ct = 0; ct < 4; ++ct) {
            bf16x8 a = *(const bf16x8*)(arow + (ct << 5));
            #pragma unroll
            for (int nt = 0; nt < 8; ++nt) {
                bf16x8 bf = *(const bf16x8*)(bbase + ((nt << 2) + ct) * 512);
                acc[nt] = __builtin_amdgcn_mfma_f32_16x16x32_bf16(a, bf, acc[nt], 0, 0, 0);
            }
        }
        __syncthreads();     // MFMA LDS reads done before next iteration overwrites
    }
    // ---- epilogue: acc -> LDS transpose -> coalesced 256B-run stores ----
    // D[m = 4*lq + r][nn = lm]: wo = wv*16 + lq*4 + r, co = nt*16 + lm
    #pragma unroll
    for (int nt = 0; nt < 8; ++nt) {
        float* orow = ot + (nt * 16 + lm) * 65 + wv * 16 + (lq << 2);
        orow[0] = acc[nt][0]; orow[1] = acc[nt][1];
        orow[2] = acc[nt][2]; orow[3] = acc[nt][3];
    }
    __syncthreads();
    int co2 = t >> 1, wo2 = (t & 1) << 5;
    const float* srow = ot + co2 * 65 + wo2;
    float* dstg = out + (((size_t)(n * COUT + co2) * H + ho) * W + wo2);
    #pragma unroll
    for (int i = 0; i < 8; ++i) {
        f32x4 v = { srow[4*i], srow[4*i+1], srow[4*i+2], srow[4*i+3] };
        *(f32x4*)(dstg + 4 * i) = v;
    }
}

extern "C" void kernel_launch(void* const* d_in, const int* in_sizes, int n_in,
                              void* d_out, int out_size, void* d_ws, size_t ws_size,
                              hipStream_t stream) {
    const float* x      = (const float*)d_in[0];   // (8,128,64,64)
    const float* offset = (const float*)d_in[1];   // (8,18,64,64)
    const float* weight = (const float*)d_in[2];   // (128,128,3,3)
    float* out = (float*)d_out;

    unsigned short* xt  = (unsigned short*)d_ws;                                  // 8 MB
    unsigned short* wtf = (unsigned short*)((char*)d_ws + (size_t)NB*H*W*CIN*2);  // 288 KB

    hipLaunchKernelGGL(prep_all, dim3(NB * H), dim3(256), 0, stream, x, weight, xt, wtf);
    hipLaunchKernelGGL(deform_main, dim3(NB * H), dim3(256), 0, stream,
                       offset, xt, wtf, out);
}